// Round 13
// baseline (282.837 us; speedup 1.0000x reference)
//
#include <hip/hip_runtime.h>
#include <math.h>

// Problem constants
#define NB    64     // batch
#define NQn   256    // queries
#define NNn   512    // nodes
#define HDn   128    // H*D = EMB
#define LOG2E 1.44269504088896340736f
#define INV_SQRT_EMB 0.08838834764831845f   // 1/sqrt(128)

__device__ __forceinline__ float4 ldg4(const float* p) {
    return *reinterpret_cast<const float4*>(p);
}

// ---------------------------------------------------------------------------
// mask_transpose v2 (proven R12-neutral): mask[b][q][n] -> maskT8[b][n][q] u8.
// ---------------------------------------------------------------------------
__global__ __launch_bounds__(256, 4)
void mask_transpose(const float* __restrict__ mask, unsigned char* __restrict__ maskT8)
{
    __shared__ float Ms[64 * 65];                   // [q][n], pad 65
    const int tid = threadIdx.x;
    const int b   = blockIdx.x;
    const int q0  = blockIdx.y * 64;
    const int n0  = blockIdx.z * 64;
    const int qg  = tid >> 6;                       // wave = q-subgroup of 16
    const int ln  = tid & 63;                       // lane = n

    #pragma unroll
    for (int j = 0; j < 16; ++j) {
        int q = qg * 16 + j;
        Ms[q * 65 + ln] = mask[((size_t)(b * NQn + q0 + q)) * NNn + n0 + ln];
    }
    __syncthreads();

    const int n  = tid >> 2;                        // 0..63
    const int qc = (tid & 3) * 16;                  // 16B q-chunk
    unsigned int u[4] = {0u, 0u, 0u, 0u};
    #pragma unroll
    for (int j = 0; j < 16; ++j) {
        float v = Ms[(qc + j) * 65 + n];
        unsigned int bit = (v != 0.0f) ? 1u : 0u;   // mask is exactly 0 or -inf
        u[j >> 2] |= bit << (8 * (j & 3));
    }
    *reinterpret_cast<uint4*>(maskT8 + ((size_t)(b * NNn + n0 + n)) * NQn + q0 + qc) =
        make_uint4(u[0], u[1], u[2], u[3]);
}

// ---------------------------------------------------------------------------
// proj_kernel (proven R3): Y[R x 128] = X[R x 128] @ W[128 x 128]
// (+ attr*wrow rank-1, + bias). grid (R/64, 2 col-halves), block 256 (4 waves).
// Optional second pass reuses the staged X tile (used for K and V).
// ---------------------------------------------------------------------------
__global__ __launch_bounds__(256, 2)
void proj_kernel(const float* __restrict__ X,
                 const float* __restrict__ W0, const float* __restrict__ W1,
                 const float* __restrict__ wrow, const float* __restrict__ attr,
                 const float* __restrict__ bias,
                 float* __restrict__ Y0, float* __restrict__ Y1)
{
    __shared__ float Xs[64 * 128];
    __shared__ float Wt[64 * 128];
    const int tid = threadIdx.x;
    const int rg = tid >> 4;          // 0..15
    const int cg = tid & 15;          // 0..15
    const int rowblk = blockIdx.x * 64;
    const int colbase = blockIdx.y * 64;

    #pragma unroll
    for (int i = 0; i < 8; ++i) {
        int idx = tid + 256 * i;      // f4 index in [0,2048)
        int r = idx >> 5;             // 32 f4 per row
        int c4 = idx & 31;
        float4 v = ldg4(X + (rowblk + r) * 128 + c4 * 4);
        *reinterpret_cast<float4*>(&Xs[r * 128 + ((c4 ^ (r & 7)) << 2)]) = v;
    }

    for (int pass = 0; pass < 2; ++pass) {
        if (pass && (W1 == nullptr)) break;
        const float* W = pass ? W1 : W0;
        float* Y = pass ? Y1 : Y0;
        __syncthreads();
        #pragma unroll
        for (int i = 0; i < 32; ++i) {
            int idx = tid + 256 * i;  // 8192 scalars
            int k = idx >> 6;         // 0..127
            int c = idx & 63;         // 0..63
            float w = W[k * 128 + colbase + c];
            Wt[c * 128 + ((((k >> 2) ^ (c & 7)) << 2) | (k & 3))] = w;
        }
        __syncthreads();

        float acc[4][4];
        #pragma unroll
        for (int r = 0; r < 4; ++r)
            #pragma unroll
            for (int c = 0; c < 4; ++c) acc[r][c] = 0.f;

        const int rsw = rg & 7;
        const int csw = cg & 7;
        #pragma unroll 8
        for (int k4 = 0; k4 < 32; ++k4) {
            float4 a[4], bv[4];
            #pragma unroll
            for (int r = 0; r < 4; ++r)
                a[r] = *reinterpret_cast<const float4*>(&Xs[(rg + 16 * r) * 128 + ((k4 ^ rsw) << 2)]);
            #pragma unroll
            for (int c = 0; c < 4; ++c)
                bv[c] = *reinterpret_cast<const float4*>(&Wt[(cg + 16 * c) * 128 + ((k4 ^ csw) << 2)]);
            #pragma unroll
            for (int r = 0; r < 4; ++r)
                #pragma unroll
                for (int c = 0; c < 4; ++c)
                    acc[r][c] += a[r].x * bv[c].x + a[r].y * bv[c].y
                               + a[r].z * bv[c].z + a[r].w * bv[c].w;
        }

        if (attr != nullptr) {
            #pragma unroll
            for (int r = 0; r < 4; ++r) {
                float av = attr[rowblk + rg + 16 * r];
                #pragma unroll
                for (int c = 0; c < 4; ++c)
                    acc[r][c] += av * wrow[colbase + cg + 16 * c];
            }
        }
        #pragma unroll
        for (int r = 0; r < 4; ++r) {
            int row = rowblk + rg + 16 * r;
            #pragma unroll
            for (int c = 0; c < 4; ++c) {
                int col = colbase + cg + 16 * c;
                float o = acc[r][c];
                if (bias != nullptr) o += bias[col];
                Y[row * 128 + col] = o;
            }
        }
    }
}

// ---------------------------------------------------------------------------
// attn_kernel (R10 v5 code, node-split count now runtime): 4 q-rows per lane,
// block 512 = 8 waves = 8 heads covering all 256 q; grid (64 b, nsplit).
// nsplit=8 (64 nodes/split, ntiles=2) -> 512 blocks = 2 blocks/CU = 16
// waves/CU = 4 waves/SIMD (VGPR=104 fits: 4x104=416<=512); nsplit=4 is the
// proven champion config (1 block/CU fallback when ws is small).
// K/V staged in LDS 32-node tiles (broadcast reads, conflict-free); mask is
// one coalesced dword/node/lane; fixed-shift softmax p=exp2(dot*0.25*log2e)
// (validated r1-r12); raw exp2. Partials -> proj_comb_kernel.
// ---------------------------------------------------------------------------
__global__ __launch_bounds__(512, 2)
void attn_kernel(const float* __restrict__ Q, const float* __restrict__ K,
                 const float* __restrict__ V, const unsigned int* __restrict__ maskTu,
                 float* __restrict__ Pbase, float* __restrict__ Lbase, int ntiles)
{
    __shared__ float Ks[32 * 128];    // 16KB
    __shared__ float Vs[32 * 128];    // 16KB
    const int tid  = threadIdx.x;
    const int lane = tid & 63;
    const int h    = tid >> 6;        // wave = head
    const int b    = blockIdx.x;
    const int ns   = blockIdx.y;
    const int nbase = ns * (ntiles * 32);

    // 4 q-fragments, pre-scaled by 0.25*log2e
    float qv[4][16];
    {
        const float sc = 0.25f * LOG2E;
        #pragma unroll
        for (int qq = 0; qq < 4; ++qq) {
            const float* qp = Q + ((size_t)(b * NQn + 4 * lane + qq)) * 128 + h * 16;
            #pragma unroll
            for (int j = 0; j < 4; ++j) {
                float4 tv = ldg4(qp + 4 * j);
                qv[qq][4 * j + 0] = tv.x * sc;
                qv[qq][4 * j + 1] = tv.y * sc;
                qv[qq][4 * j + 2] = tv.z * sc;
                qv[qq][4 * j + 3] = tv.w * sc;
            }
        }
    }

    float out[4][16];
    #pragma unroll
    for (int qq = 0; qq < 4; ++qq)
        #pragma unroll
        for (int d = 0; d < 16; ++d) out[qq][d] = 0.f;
    float ls[4] = {0.f, 0.f, 0.f, 0.f};

    // per-node mask dword (4 q bytes) for this lane
    const unsigned int* mbase = maskTu + (((size_t)(b * NNn + nbase) * NQn) >> 2) + lane;

    for (int t = 0; t < ntiles; ++t) {
        __syncthreads();
        {   // stage 32-node K/V tile: 2 f4/thread each, fully coalesced, linear
            const float* kg = K + ((size_t)(b * NNn + nbase + t * 32)) * 128;
            const float* vg = V + ((size_t)(b * NNn + nbase + t * 32)) * 128;
            float4 k0 = ldg4(kg + tid * 4);
            float4 k1 = ldg4(kg + (tid + 512) * 4);
            float4 v0 = ldg4(vg + tid * 4);
            float4 v1 = ldg4(vg + (tid + 512) * 4);
            *reinterpret_cast<float4*>(&Ks[tid * 4]) = k0;
            *reinterpret_cast<float4*>(&Ks[(tid + 512) * 4]) = k1;
            *reinterpret_cast<float4*>(&Vs[tid * 4]) = v0;
            *reinterpret_cast<float4*>(&Vs[(tid + 512) * 4]) = v1;
        }
        __syncthreads();

        const float* kbase = &Ks[h * 16];
        const float* vbase = &Vs[h * 16];
        for (int n = 0; n < 32; ++n) {
            const float* kr = kbase + n * 128;
            const float* vr = vbase + n * 128;
            float kf[16], vf[16];
            *reinterpret_cast<float4*>(&kf[0])  = *reinterpret_cast<const float4*>(kr);
            *reinterpret_cast<float4*>(&kf[4])  = *reinterpret_cast<const float4*>(kr + 4);
            *reinterpret_cast<float4*>(&kf[8])  = *reinterpret_cast<const float4*>(kr + 8);
            *reinterpret_cast<float4*>(&kf[12]) = *reinterpret_cast<const float4*>(kr + 12);
            *reinterpret_cast<float4*>(&vf[0])  = *reinterpret_cast<const float4*>(vr);
            *reinterpret_cast<float4*>(&vf[4])  = *reinterpret_cast<const float4*>(vr + 4);
            *reinterpret_cast<float4*>(&vf[8])  = *reinterpret_cast<const float4*>(vr + 8);
            *reinterpret_cast<float4*>(&vf[12]) = *reinterpret_cast<const float4*>(vr + 12);
            unsigned int m4 = mbase[(t * 32 + n) * (NQn / 4)];

            float p[4];
            #pragma unroll
            for (int qq = 0; qq < 4; ++qq) {
                float aP = qv[qq][0]*kf[0] + qv[qq][1]*kf[1] + qv[qq][2]*kf[2] + qv[qq][3]*kf[3];
                float aQ = qv[qq][4]*kf[4] + qv[qq][5]*kf[5] + qv[qq][6]*kf[6] + qv[qq][7]*kf[7];
                float aR = qv[qq][8]*kf[8] + qv[qq][9]*kf[9] + qv[qq][10]*kf[10] + qv[qq][11]*kf[11];
                float aS = qv[qq][12]*kf[12] + qv[qq][13]*kf[13] + qv[qq][14]*kf[14] + qv[qq][15]*kf[15];
                p[qq] = __builtin_amdgcn_exp2f((aP + aQ) + (aR + aS));
            }
            p[0] = (m4 & 0x000000ffu) ? 0.f : p[0];   // masked -> 0
            p[1] = (m4 & 0x0000ff00u) ? 0.f : p[1];
            p[2] = (m4 & 0x00ff0000u) ? 0.f : p[2];
            p[3] = (m4 & 0xff000000u) ? 0.f : p[3];
            ls[0] += p[0]; ls[1] += p[1]; ls[2] += p[2]; ls[3] += p[3];
            #pragma unroll
            for (int d = 0; d < 16; ++d) {
                out[0][d] += p[0] * vf[d];
                out[1][d] += p[1] * vf[d];
                out[2][d] += p[2] * vf[d];
                out[3][d] += p[3] * vf[d];
            }
        }
    }

    float* P = Pbase + (size_t)ns * NB * NQn * 128;
    float* L = Lbase + (size_t)ns * NB * NQn * 8;
    #pragma unroll
    for (int qq = 0; qq < 4; ++qq) {
        float* op = P + ((size_t)(b * NQn + 4 * lane + qq)) * 128 + h * 16;
        *reinterpret_cast<float4*>(op)      = make_float4(out[qq][0],  out[qq][1],  out[qq][2],  out[qq][3]);
        *reinterpret_cast<float4*>(op + 4)  = make_float4(out[qq][4],  out[qq][5],  out[qq][6],  out[qq][7]);
        *reinterpret_cast<float4*>(op + 8)  = make_float4(out[qq][8],  out[qq][9],  out[qq][10], out[qq][11]);
        *reinterpret_cast<float4*>(op + 12) = make_float4(out[qq][12], out[qq][13], out[qq][14], out[qq][15]);
        L[(b * NQn + 4 * lane + qq) * 8 + h] = ls[qq];
    }
}

// ---------------------------------------------------------------------------
// proj_comb_kernel (R10 structure, nsplit runtime): MH = merge(P,L) @ Wcomb
// + bias, node-split merge folded into the X-tile staging. Fully-masked rows
// (l==0) -> V[b][node 0] slice.
// ---------------------------------------------------------------------------
__global__ __launch_bounds__(256, 2)
void proj_comb_kernel(const float* __restrict__ Pbase, const float* __restrict__ Lbase,
                      int nsplit, const float* __restrict__ V,
                      const float* __restrict__ W0, const float* __restrict__ bias,
                      float* __restrict__ Y0)
{
    __shared__ float Xs[64 * 128];
    __shared__ float Wt[64 * 128];
    const int tid = threadIdx.x;
    const int rg = tid >> 4;
    const int cg = tid & 15;
    const int rowblk = blockIdx.x * 64;
    const int colbase = blockIdx.y * 64;
    const size_t PS = (size_t)NB * NQn * 128;
    const size_t LS = (size_t)NB * NQn * 8;

    #pragma unroll
    for (int i = 0; i < 8; ++i) {
        int idx = tid + 256 * i;      // f4 index in [0,2048)
        int r = idx >> 5;
        int c4 = idx & 31;
        int row = rowblk + r;         // b*NQ + q
        int hh = c4 >> 2;
        float l = 0.f;
        for (int s = 0; s < nsplit; ++s)
            l += Lbase[s * LS + row * 8 + hh];
        float4 v;
        if (l == 0.0f) {              // fully-masked row: weights one-hot at node 0
            v = ldg4(V + ((size_t)(row >> 8)) * NNn * 128 + c4 * 4);
        } else {
            float sx = 0.f, sy = 0.f, sz = 0.f, sw = 0.f;
            for (int s = 0; s < nsplit; ++s) {
                float4 a = ldg4(Pbase + s * PS + (size_t)row * 128 + c4 * 4);
                sx += a.x; sy += a.y; sz += a.z; sw += a.w;
            }
            float inv = __builtin_amdgcn_rcpf(l);
            v = make_float4(sx * inv, sy * inv, sz * inv, sw * inv);
        }
        *reinterpret_cast<float4*>(&Xs[r * 128 + ((c4 ^ (r & 7)) << 2)]) = v;
    }

    __syncthreads();
    #pragma unroll
    for (int i = 0; i < 32; ++i) {
        int idx = tid + 256 * i;
        int k = idx >> 6;
        int c = idx & 63;
        float w = W0[k * 128 + colbase + c];
        Wt[c * 128 + ((((k >> 2) ^ (c & 7)) << 2) | (k & 3))] = w;
    }
    __syncthreads();

    float acc[4][4];
    #pragma unroll
    for (int r = 0; r < 4; ++r)
        #pragma unroll
        for (int c = 0; c < 4; ++c) acc[r][c] = 0.f;

    const int rsw = rg & 7;
    const int csw = cg & 7;
    #pragma unroll 8
    for (int k4 = 0; k4 < 32; ++k4) {
        float4 a[4], bv[4];
        #pragma unroll
        for (int r = 0; r < 4; ++r)
            a[r] = *reinterpret_cast<const float4*>(&Xs[(rg + 16 * r) * 128 + ((k4 ^ rsw) << 2)]);
        #pragma unroll
        for (int c = 0; c < 4; ++c)
            bv[c] = *reinterpret_cast<const float4*>(&Wt[(cg + 16 * c) * 128 + ((k4 ^ csw) << 2)]);
        #pragma unroll
        for (int r = 0; r < 4; ++r)
            #pragma unroll
            for (int c = 0; c < 4; ++c)
                acc[r][c] += a[r].x * bv[c].x + a[r].y * bv[c].y
                           + a[r].z * bv[c].z + a[r].w * bv[c].w;
    }

    #pragma unroll
    for (int r = 0; r < 4; ++r) {
        int row = rowblk + rg + 16 * r;
        #pragma unroll
        for (int c = 0; c < 4; ++c) {
            int col = colbase + cg + 16 * c;
            Y0[row * 128 + col] = acc[r][c] + bias[col];
        }
    }
}

// ---------------------------------------------------------------------------
// final_kernel v3: probs = softmax(10*tanh(MH@EN^T/sqrt128)+mask).
// 1024-thread block, q-tile stays 64 -> grid stays 256 (EN staging stays 1x,
// unlike the R4/R11 q-tile-32 attempts that doubled staging) but 16 waves/CU
// instead of 8. One q-row per thread (qg 0..63), mg 16 lanes over m;
// pr[32] static, ~90 regs under bounds(1024,4)'s 128 cap.
// ---------------------------------------------------------------------------
__global__ __launch_bounds__(1024, 4)
void final_kernel(const float* __restrict__ MH, const float* __restrict__ EN,
                  const float* __restrict__ mask, float* __restrict__ OUT)
{
    __shared__ float ENs[128 * 128];
    const int tid = threadIdx.x;
    const int qg = tid >> 4;          // 0..63 (1 q-row each)
    const int mg = tid & 15;          // 0..15 (m = mg + 16c)
    const int b  = blockIdx.x >> 2;
    const int q0 = (blockIdx.x & 3) * 64;

    const float* mhrow = MH + (b * NQn + q0 + qg) * 128;
    float pr[32];
    float psum = 0.f;
    const int msw = mg & 7;

    #pragma unroll
    for (int t = 0; t < 4; ++t) {
        const int m0 = t * 128;
        __syncthreads();
        #pragma unroll
        for (int i = 0; i < 4; ++i) {
            int idx = tid + 1024 * i;
            int r = idx >> 5;
            int c4 = idx & 31;
            float4 v = ldg4(EN + (b * NNn + m0 + r) * 128 + c4 * 4);
            *reinterpret_cast<float4*>(&ENs[r * 128 + ((c4 ^ (r & 7)) << 2)]) = v;
        }
        __syncthreads();

        float acc[8];
        #pragma unroll
        for (int c = 0; c < 8; ++c) acc[c] = 0.f;

        #pragma unroll 4
        for (int k4 = 0; k4 < 32; ++k4) {
            float4 a0 = ldg4(mhrow + k4 * 4);      // L1-resident, 16-lane broadcast
            float4 bv[8];
            #pragma unroll
            for (int c = 0; c < 8; ++c)
                bv[c] = *reinterpret_cast<const float4*>(&ENs[(mg + 16 * c) * 128 + ((k4 ^ msw) << 2)]);
            #pragma unroll
            for (int c = 0; c < 8; ++c)
                acc[c] += a0.x*bv[c].x + a0.y*bv[c].y + a0.z*bv[c].z + a0.w*bv[c].w;
        }

        const float* mrow = mask + (b * NQn + q0 + qg) * NNn + m0;
        #pragma unroll
        for (int c = 0; c < 8; ++c) {
            int m = mg + 16 * c;
            float s2 = acc[c] * INV_SQRT_EMB;
            float e  = __builtin_amdgcn_exp2f(s2 * (2.0f * LOG2E));       // saturates fine
            float rc = __builtin_amdgcn_rcpf(e + 1.0f);
            float mv = mrow[m];
            float pv = __builtin_amdgcn_exp2f((mv - 20.0f * rc) * LOG2E); // -inf -> 0
            pr[t * 8 + c] = pv;
            psum += pv;
        }
    }

    {   // row-sum across the 16 mg lanes (lanes qg*16..qg*16+15 consecutive)
        float s = psum;
        s += __shfl_xor(s, 1);
        s += __shfl_xor(s, 2);
        s += __shfl_xor(s, 4);
        s += __shfl_xor(s, 8);
        psum = s;
    }

    float* orow = OUT + (b * NQn + q0 + qg) * NNn;
    if (psum == 0.0f) {               // fully-masked row -> one-hot at m=0
        #pragma unroll
        for (int t = 0; t < 4; ++t)
            #pragma unroll
            for (int c = 0; c < 8; ++c) {
                int m = t * 128 + mg + 16 * c;
                orow[m] = (m == 0) ? 1.0f : 0.0f;
            }
    } else {
        float inv = __builtin_amdgcn_rcpf(psum);
        #pragma unroll
        for (int t = 0; t < 4; ++t)
            #pragma unroll
            for (int c = 0; c < 8; ++c)
                orow[t * 128 + mg + 16 * c] = pr[t * 8 + c] * inv;
    }
}

// ---------------------------------------------------------------------------
extern "C" void kernel_launch(void* const* d_in, const int* in_sizes, int n_in,
                              void* d_out, int out_size, void* d_ws, size_t ws_size,
                              hipStream_t stream) {
    const float* enc_last  = (const float*)d_in[0];   // [B,NQ,128]
    const float* attr      = (const float*)d_in[1];   // [B,NQ,1]
    const float* enc_nodes = (const float*)d_in[2];   // [B,NN,128]
    const float* mask      = (const float*)d_in[3];   // [B,NQ,NN]
    const float* Wq        = (const float*)d_in[4];   // [129,128]
    const float* Wk        = (const float*)d_in[5];   // [128,128]
    const float* Wv        = (const float*)d_in[6];   // [128,128]
    const float* Wcomb     = (const float*)d_in[7];   // [128,128]
    const float* bcomb     = (const float*)d_in[8];   // [128]
    float* out = (float*)d_out;

    const size_t PS = (size_t)NB * NQn * 128;   // 8.39 MB / split
    const size_t LS = (size_t)NB * NQn * 8;     // 0.52 MB / split
    const size_t KVQ = (size_t)NB * NNn * 128 * 2 + (size_t)NB * NQn * 128;
    // ws needed for nsplit splits:
    //   K+V+Q + nsplit*(P+L) + maskT8
    const size_t need8 = (KVQ + 8 * (PS + LS)) * 4 + (size_t)NB * NNn * NQn;
    const int nsplit = (ws_size >= need8) ? 8 : 4;   // ws_size fixed -> deterministic
    const int ntiles = (nsplit == 8) ? 2 : 4;        // 32-node tiles per split

    float* Kbuf  = (float*)d_ws;                        // [B*NN,128] 16.8MB
    float* Vbuf  = Kbuf + (size_t)NB * NNn * 128;       // [B*NN,128] 16.8MB
    float* Qbuf  = Vbuf + (size_t)NB * NNn * 128;       // [B*NQ,128]  8.4MB
    float* Pbase = Qbuf + (size_t)NB * NQn * 128;       // nsplit x 8.4MB
    float* Lbase = Pbase + (size_t)nsplit * PS;         // nsplit x 0.5MB
    unsigned char* maskT8 = (unsigned char*)(Lbase + (size_t)nsplit * LS);  // 8.4MB
    float* MH    = Qbuf;  // alias: Qbuf dead after attn; proj_comb writes, final reads

    // mask -> transposed u8 [b][n][q]
    mask_transpose<<<dim3(NB, NQn / 64, NNn / 64), 256, 0, stream>>>(mask, maskT8);
    // K,V projections (dual-pass over shared X tile)
    proj_kernel<<<dim3(NB * NNn / 64, 2), 256, 0, stream>>>(
        enc_nodes, Wk, Wv, nullptr, nullptr, nullptr, Kbuf, Vbuf);
    // Q projection (concat attr handled as rank-1 term with Wq row 128)
    proj_kernel<<<dim3(NB * NQn / 64, 2), 256, 0, stream>>>(
        enc_last, Wq, nullptr, Wq + 128 * 128, attr, nullptr, Qbuf, nullptr);
    // masked multi-head attention: 4q/lane, nsplit node-splits
    attn_kernel<<<dim3(NB, nsplit), 512, 0, stream>>>(
        Qbuf, Kbuf, Vbuf, (const unsigned int*)maskT8, Pbase, Lbase, ntiles);
    // combine projection + bias, nsplit-way merge fused into staging
    proj_comb_kernel<<<dim3(NB * NQn / 64, 2), 256, 0, stream>>>(
        Pbase, Lbase, nsplit, Vbuf, Wcomb, bcomb, MH);
    // compatibility score + tanh clip + masked softmax (1024-thr, 16 waves/CU)
    final_kernel<<<dim3(NB * NQn / 64), 1024, 0, stream>>>(
        MH, enc_nodes, mask, out);
}

// Round 14
// 229.809 us; speedup vs baseline: 1.2308x; 1.2308x over previous
//
#include <hip/hip_runtime.h>
#include <math.h>

// Problem constants
#define NB    64     // batch
#define NQn   256    // queries
#define NNn   512    // nodes
#define HDn   128    // H*D = EMB
#define LOG2E 1.44269504088896340736f
#define INV_SQRT_EMB 0.08838834764831845f   // 1/sqrt(128)

__device__ __forceinline__ float4 ldg4(const float* p) {
    return *reinterpret_cast<const float4*>(p);
}

// ---------------------------------------------------------------------------
// mask_transpose v2: mask[b][q][n] (f32, 0/-inf) -> maskT8[b][n][q] (u8 0/1).
// LDS-staged transpose: coalesced 256B reads, full 64B-sector writes.
// ---------------------------------------------------------------------------
__global__ __launch_bounds__(256, 4)
void mask_transpose(const float* __restrict__ mask, unsigned char* __restrict__ maskT8)
{
    __shared__ float Ms[64 * 65];                   // [q][n], pad 65
    const int tid = threadIdx.x;
    const int b   = blockIdx.x;
    const int q0  = blockIdx.y * 64;
    const int n0  = blockIdx.z * 64;
    const int qg  = tid >> 6;                       // wave = q-subgroup of 16
    const int ln  = tid & 63;                       // lane = n

    #pragma unroll
    for (int j = 0; j < 16; ++j) {
        int q = qg * 16 + j;
        Ms[q * 65 + ln] = mask[((size_t)(b * NQn + q0 + q)) * NNn + n0 + ln];
    }
    __syncthreads();

    const int n  = tid >> 2;                        // 0..63
    const int qc = (tid & 3) * 16;                  // 16B q-chunk
    unsigned int u[4] = {0u, 0u, 0u, 0u};
    #pragma unroll
    for (int j = 0; j < 16; ++j) {
        float v = Ms[(qc + j) * 65 + n];
        unsigned int bit = (v != 0.0f) ? 1u : 0u;   // mask is exactly 0 or -inf
        u[j >> 2] |= bit << (8 * (j & 3));
    }
    *reinterpret_cast<uint4*>(maskT8 + ((size_t)(b * NNn + n0 + n)) * NQn + q0 + qc) =
        make_uint4(u[0], u[1], u[2], u[3]);
}

// ---------------------------------------------------------------------------
// proj_kernel (proven R3): Y[R x 128] = X[R x 128] @ W[128 x 128]
// (+ attr*wrow rank-1, + bias). grid (R/64, 2 col-halves), block 256 (4 waves).
// Optional second pass reuses the staged X tile (used for K and V).
// ---------------------------------------------------------------------------
__global__ __launch_bounds__(256, 2)
void proj_kernel(const float* __restrict__ X,
                 const float* __restrict__ W0, const float* __restrict__ W1,
                 const float* __restrict__ wrow, const float* __restrict__ attr,
                 const float* __restrict__ bias,
                 float* __restrict__ Y0, float* __restrict__ Y1)
{
    __shared__ float Xs[64 * 128];
    __shared__ float Wt[64 * 128];
    const int tid = threadIdx.x;
    const int rg = tid >> 4;          // 0..15
    const int cg = tid & 15;          // 0..15
    const int rowblk = blockIdx.x * 64;
    const int colbase = blockIdx.y * 64;

    #pragma unroll
    for (int i = 0; i < 8; ++i) {
        int idx = tid + 256 * i;      // f4 index in [0,2048)
        int r = idx >> 5;             // 32 f4 per row
        int c4 = idx & 31;
        float4 v = ldg4(X + (rowblk + r) * 128 + c4 * 4);
        *reinterpret_cast<float4*>(&Xs[r * 128 + ((c4 ^ (r & 7)) << 2)]) = v;
    }

    for (int pass = 0; pass < 2; ++pass) {
        if (pass && (W1 == nullptr)) break;
        const float* W = pass ? W1 : W0;
        float* Y = pass ? Y1 : Y0;
        __syncthreads();
        #pragma unroll
        for (int i = 0; i < 32; ++i) {
            int idx = tid + 256 * i;  // 8192 scalars
            int k = idx >> 6;         // 0..127
            int c = idx & 63;         // 0..63
            float w = W[k * 128 + colbase + c];
            Wt[c * 128 + ((((k >> 2) ^ (c & 7)) << 2) | (k & 3))] = w;
        }
        __syncthreads();

        float acc[4][4];
        #pragma unroll
        for (int r = 0; r < 4; ++r)
            #pragma unroll
            for (int c = 0; c < 4; ++c) acc[r][c] = 0.f;

        const int rsw = rg & 7;
        const int csw = cg & 7;
        #pragma unroll 8
        for (int k4 = 0; k4 < 32; ++k4) {
            float4 a[4], bv[4];
            #pragma unroll
            for (int r = 0; r < 4; ++r)
                a[r] = *reinterpret_cast<const float4*>(&Xs[(rg + 16 * r) * 128 + ((k4 ^ rsw) << 2)]);
            #pragma unroll
            for (int c = 0; c < 4; ++c)
                bv[c] = *reinterpret_cast<const float4*>(&Wt[(cg + 16 * c) * 128 + ((k4 ^ csw) << 2)]);
            #pragma unroll
            for (int r = 0; r < 4; ++r)
                #pragma unroll
                for (int c = 0; c < 4; ++c)
                    acc[r][c] += a[r].x * bv[c].x + a[r].y * bv[c].y
                               + a[r].z * bv[c].z + a[r].w * bv[c].w;
        }

        if (attr != nullptr) {
            #pragma unroll
            for (int r = 0; r < 4; ++r) {
                float av = attr[rowblk + rg + 16 * r];
                #pragma unroll
                for (int c = 0; c < 4; ++c)
                    acc[r][c] += av * wrow[colbase + cg + 16 * c];
            }
        }
        #pragma unroll
        for (int r = 0; r < 4; ++r) {
            int row = rowblk + rg + 16 * r;
            #pragma unroll
            for (int c = 0; c < 4; ++c) {
                int col = colbase + cg + 16 * c;
                float o = acc[r][c];
                if (bias != nullptr) o += bias[col];
                Y[row * 128 + col] = o;
            }
        }
    }
}

// ---------------------------------------------------------------------------
// attn_kernel (champion R10, 92us, VGPR=104 no-spill): 4 q-rows per lane ->
// 4x reuse of every K/V LDS broadcast. Block 512 = 8 waves = 8 heads covering
// all 256 q (q = 4*lane+qq); grid (64 b, 4 node-splits of 128) = 1 block/CU.
// K/V staged in LDS in 32-node tiles (broadcast reads, conflict-free). Mask
// read as ONE coalesced dword/node/lane from the transposed u8 tensor;
// masked -> p=0 via cndmask (no -inf arithmetic). Fixed-shift softmax:
// p = exp2(dot*0.25*log2e) (scores sigma~0.33, validated r1-r13); raw
// __builtin_amdgcn_exp2f (inputs bounded). Partials -> proj_comb_kernel.
// Session evidence: this is a genuine local optimum — occupancy splits (r11,
// r13), ILP/unroll (r4, r9), asm SGPR (r6), and 128-reg 4q (r7) all regressed.
// ---------------------------------------------------------------------------
__global__ __launch_bounds__(512, 2)
void attn_kernel(const float* __restrict__ Q, const float* __restrict__ K,
                 const float* __restrict__ V, const unsigned int* __restrict__ maskTu,
                 float* __restrict__ P0, float* __restrict__ P1,
                 float* __restrict__ P2, float* __restrict__ P3,
                 float* __restrict__ L0, float* __restrict__ L1,
                 float* __restrict__ L2, float* __restrict__ L3)
{
    __shared__ float Ks[32 * 128];    // 16KB
    __shared__ float Vs[32 * 128];    // 16KB
    const int tid  = threadIdx.x;
    const int lane = tid & 63;
    const int h    = tid >> 6;        // wave = head
    const int b    = blockIdx.x;
    const int ns   = blockIdx.y;
    const int nbase = ns * 128;

    // 4 q-fragments, pre-scaled by 0.25*log2e
    float qv[4][16];
    {
        const float sc = 0.25f * LOG2E;
        #pragma unroll
        for (int qq = 0; qq < 4; ++qq) {
            const float* qp = Q + ((size_t)(b * NQn + 4 * lane + qq)) * 128 + h * 16;
            #pragma unroll
            for (int j = 0; j < 4; ++j) {
                float4 tv = ldg4(qp + 4 * j);
                qv[qq][4 * j + 0] = tv.x * sc;
                qv[qq][4 * j + 1] = tv.y * sc;
                qv[qq][4 * j + 2] = tv.z * sc;
                qv[qq][4 * j + 3] = tv.w * sc;
            }
        }
    }

    float out[4][16];
    #pragma unroll
    for (int qq = 0; qq < 4; ++qq)
        #pragma unroll
        for (int d = 0; d < 16; ++d) out[qq][d] = 0.f;
    float ls[4] = {0.f, 0.f, 0.f, 0.f};

    // per-node mask dword (4 q bytes) for this lane
    const unsigned int* mbase = maskTu + (((size_t)(b * NNn + nbase) * NQn) >> 2) + lane;

    for (int t = 0; t < 4; ++t) {
        __syncthreads();
        {   // stage 32-node K/V tile: 2 f4/thread each, fully coalesced, linear
            const float* kg = K + ((size_t)(b * NNn + nbase + t * 32)) * 128;
            const float* vg = V + ((size_t)(b * NNn + nbase + t * 32)) * 128;
            float4 k0 = ldg4(kg + tid * 4);
            float4 k1 = ldg4(kg + (tid + 512) * 4);
            float4 v0 = ldg4(vg + tid * 4);
            float4 v1 = ldg4(vg + (tid + 512) * 4);
            *reinterpret_cast<float4*>(&Ks[tid * 4]) = k0;
            *reinterpret_cast<float4*>(&Ks[(tid + 512) * 4]) = k1;
            *reinterpret_cast<float4*>(&Vs[tid * 4]) = v0;
            *reinterpret_cast<float4*>(&Vs[(tid + 512) * 4]) = v1;
        }
        __syncthreads();

        const float* kbase = &Ks[h * 16];
        const float* vbase = &Vs[h * 16];
        for (int n = 0; n < 32; ++n) {
            const float* kr = kbase + n * 128;
            const float* vr = vbase + n * 128;
            float kf[16], vf[16];
            *reinterpret_cast<float4*>(&kf[0])  = *reinterpret_cast<const float4*>(kr);
            *reinterpret_cast<float4*>(&kf[4])  = *reinterpret_cast<const float4*>(kr + 4);
            *reinterpret_cast<float4*>(&kf[8])  = *reinterpret_cast<const float4*>(kr + 8);
            *reinterpret_cast<float4*>(&kf[12]) = *reinterpret_cast<const float4*>(kr + 12);
            *reinterpret_cast<float4*>(&vf[0])  = *reinterpret_cast<const float4*>(vr);
            *reinterpret_cast<float4*>(&vf[4])  = *reinterpret_cast<const float4*>(vr + 4);
            *reinterpret_cast<float4*>(&vf[8])  = *reinterpret_cast<const float4*>(vr + 8);
            *reinterpret_cast<float4*>(&vf[12]) = *reinterpret_cast<const float4*>(vr + 12);
            unsigned int m4 = mbase[(t * 32 + n) * (NQn / 4)];

            float p[4];
            #pragma unroll
            for (int qq = 0; qq < 4; ++qq) {
                float aP = qv[qq][0]*kf[0] + qv[qq][1]*kf[1] + qv[qq][2]*kf[2] + qv[qq][3]*kf[3];
                float aQ = qv[qq][4]*kf[4] + qv[qq][5]*kf[5] + qv[qq][6]*kf[6] + qv[qq][7]*kf[7];
                float aR = qv[qq][8]*kf[8] + qv[qq][9]*kf[9] + qv[qq][10]*kf[10] + qv[qq][11]*kf[11];
                float aS = qv[qq][12]*kf[12] + qv[qq][13]*kf[13] + qv[qq][14]*kf[14] + qv[qq][15]*kf[15];
                p[qq] = __builtin_amdgcn_exp2f((aP + aQ) + (aR + aS));
            }
            p[0] = (m4 & 0x000000ffu) ? 0.f : p[0];   // masked -> 0
            p[1] = (m4 & 0x0000ff00u) ? 0.f : p[1];
            p[2] = (m4 & 0x00ff0000u) ? 0.f : p[2];
            p[3] = (m4 & 0xff000000u) ? 0.f : p[3];
            ls[0] += p[0]; ls[1] += p[1]; ls[2] += p[2]; ls[3] += p[3];
            #pragma unroll
            for (int d = 0; d < 16; ++d) {
                out[0][d] += p[0] * vf[d];
                out[1][d] += p[1] * vf[d];
                out[2][d] += p[2] * vf[d];
                out[3][d] += p[3] * vf[d];
            }
        }
    }

    float* P = (ns == 0) ? P0 : (ns == 1) ? P1 : (ns == 2) ? P2 : P3;
    float* L = (ns == 0) ? L0 : (ns == 1) ? L1 : (ns == 2) ? L2 : L3;
    #pragma unroll
    for (int qq = 0; qq < 4; ++qq) {
        float* op = P + ((size_t)(b * NQn + 4 * lane + qq)) * 128 + h * 16;
        *reinterpret_cast<float4*>(op)      = make_float4(out[qq][0],  out[qq][1],  out[qq][2],  out[qq][3]);
        *reinterpret_cast<float4*>(op + 4)  = make_float4(out[qq][4],  out[qq][5],  out[qq][6],  out[qq][7]);
        *reinterpret_cast<float4*>(op + 8)  = make_float4(out[qq][8],  out[qq][9],  out[qq][10], out[qq][11]);
        *reinterpret_cast<float4*>(op + 12) = make_float4(out[qq][12], out[qq][13], out[qq][14], out[qq][15]);
        L[(b * NQn + 4 * lane + qq) * 8 + h] = ls[qq];
    }
}

// ---------------------------------------------------------------------------
// proj_comb_kernel (proven R10): MH = merge(P0..P3; L0..L3) @ Wcomb + bias,
// 4-way node-split merge folded into the X-tile staging. Fully-masked rows
// (l==0) -> V[b][node 0] slice.
// ---------------------------------------------------------------------------
__global__ __launch_bounds__(256, 2)
void proj_comb_kernel(const float* __restrict__ P0, const float* __restrict__ P1,
                      const float* __restrict__ P2, const float* __restrict__ P3,
                      const float* __restrict__ L0, const float* __restrict__ L1,
                      const float* __restrict__ L2, const float* __restrict__ L3,
                      const float* __restrict__ V,
                      const float* __restrict__ W0, const float* __restrict__ bias,
                      float* __restrict__ Y0)
{
    __shared__ float Xs[64 * 128];
    __shared__ float Wt[64 * 128];
    const int tid = threadIdx.x;
    const int rg = tid >> 4;
    const int cg = tid & 15;
    const int rowblk = blockIdx.x * 64;
    const int colbase = blockIdx.y * 64;

    #pragma unroll
    for (int i = 0; i < 8; ++i) {
        int idx = tid + 256 * i;      // f4 index in [0,2048)
        int r = idx >> 5;
        int c4 = idx & 31;
        int row = rowblk + r;         // b*NQ + q
        int hh = c4 >> 2;
        float l = (L0[row * 8 + hh] + L1[row * 8 + hh])
                + (L2[row * 8 + hh] + L3[row * 8 + hh]);
        float4 v;
        if (l == 0.0f) {              // fully-masked row: weights one-hot at node 0
            v = ldg4(V + ((size_t)(row >> 8)) * NNn * 128 + c4 * 4);
        } else {
            float4 a = ldg4(P0 + (size_t)row * 128 + c4 * 4);
            float4 c = ldg4(P1 + (size_t)row * 128 + c4 * 4);
            float4 d = ldg4(P2 + (size_t)row * 128 + c4 * 4);
            float4 e = ldg4(P3 + (size_t)row * 128 + c4 * 4);
            float inv = __builtin_amdgcn_rcpf(l);
            v = make_float4((a.x + c.x + d.x + e.x) * inv,
                            (a.y + c.y + d.y + e.y) * inv,
                            (a.z + c.z + d.z + e.z) * inv,
                            (a.w + c.w + d.w + e.w) * inv);
        }
        *reinterpret_cast<float4*>(&Xs[r * 128 + ((c4 ^ (r & 7)) << 2)]) = v;
    }

    __syncthreads();
    #pragma unroll
    for (int i = 0; i < 32; ++i) {
        int idx = tid + 256 * i;
        int k = idx >> 6;
        int c = idx & 63;
        float w = W0[k * 128 + colbase + c];
        Wt[c * 128 + ((((k >> 2) ^ (c & 7)) << 2) | (k & 3))] = w;
    }
    __syncthreads();

    float acc[4][4];
    #pragma unroll
    for (int r = 0; r < 4; ++r)
        #pragma unroll
        for (int c = 0; c < 4; ++c) acc[r][c] = 0.f;

    const int rsw = rg & 7;
    const int csw = cg & 7;
    #pragma unroll 8
    for (int k4 = 0; k4 < 32; ++k4) {
        float4 a[4], bv[4];
        #pragma unroll
        for (int r = 0; r < 4; ++r)
            a[r] = *reinterpret_cast<const float4*>(&Xs[(rg + 16 * r) * 128 + ((k4 ^ rsw) << 2)]);
        #pragma unroll
        for (int c = 0; c < 4; ++c)
            bv[c] = *reinterpret_cast<const float4*>(&Wt[(cg + 16 * c) * 128 + ((k4 ^ csw) << 2)]);
        #pragma unroll
        for (int r = 0; r < 4; ++r)
            #pragma unroll
            for (int c = 0; c < 4; ++c)
                acc[r][c] += a[r].x * bv[c].x + a[r].y * bv[c].y
                           + a[r].z * bv[c].z + a[r].w * bv[c].w;
    }

    #pragma unroll
    for (int r = 0; r < 4; ++r) {
        int row = rowblk + rg + 16 * r;
        #pragma unroll
        for (int c = 0; c < 4; ++c) {
            int col = colbase + cg + 16 * c;
            Y0[row * 128 + col] = acc[r][c] + bias[col];
        }
    }
}

// ---------------------------------------------------------------------------
// final_kernel (proven R3/R10): probs = softmax(10*tanh(MH@EN^T/sqrt128)+mask).
// grid B*NQ/64, block 512 (8 waves): 64 q-rows (2/thread), full 512 m.
// EN m-tiles of 128 in 64KB swizzled LDS; fixed softmax shift; pr static.
// ---------------------------------------------------------------------------
__global__ __launch_bounds__(512, 2)
void final_kernel(const float* __restrict__ MH, const float* __restrict__ EN,
                  const float* __restrict__ mask, float* __restrict__ OUT)
{
    __shared__ float ENs[128 * 128];
    const int tid = threadIdx.x;
    const int qg = tid >> 4;          // 0..31 (2 q-rows each)
    const int mg = tid & 15;          // 0..15
    const int b  = blockIdx.x >> 2;
    const int q0 = (blockIdx.x & 3) * 64;

    const float* mhbase = MH + (b * NQn + q0) * 128;
    float pr[2][32];
    float psum[2] = {0.f, 0.f};
    const int msw = mg & 7;

    #pragma unroll
    for (int t = 0; t < 4; ++t) {
        const int m0 = t * 128;
        __syncthreads();
        #pragma unroll
        for (int i = 0; i < 8; ++i) {
            int idx = tid + 512 * i;
            int r = idx >> 5;
            int c4 = idx & 31;
            float4 v = ldg4(EN + (b * NNn + m0 + r) * 128 + c4 * 4);
            *reinterpret_cast<float4*>(&ENs[r * 128 + ((c4 ^ (r & 7)) << 2)]) = v;
        }
        __syncthreads();

        float acc[2][8];
        #pragma unroll
        for (int qq = 0; qq < 2; ++qq)
            #pragma unroll
            for (int c = 0; c < 8; ++c) acc[qq][c] = 0.f;

        #pragma unroll 4
        for (int k4 = 0; k4 < 32; ++k4) {
            float4 a0 = ldg4(mhbase + (qg * 2 + 0) * 128 + k4 * 4);
            float4 a1 = ldg4(mhbase + (qg * 2 + 1) * 128 + k4 * 4);
            float4 bv[8];
            #pragma unroll
            for (int c = 0; c < 8; ++c)
                bv[c] = *reinterpret_cast<const float4*>(&ENs[(mg + 16 * c) * 128 + ((k4 ^ msw) << 2)]);
            #pragma unroll
            for (int c = 0; c < 8; ++c) {
                acc[0][c] += a0.x*bv[c].x + a0.y*bv[c].y + a0.z*bv[c].z + a0.w*bv[c].w;
                acc[1][c] += a1.x*bv[c].x + a1.y*bv[c].y + a1.z*bv[c].z + a1.w*bv[c].w;
            }
        }

        #pragma unroll
        for (int qq = 0; qq < 2; ++qq) {
            const int q = q0 + qg * 2 + qq;
            const float* mrow = mask + (b * NQn + q) * NNn + m0;
            #pragma unroll
            for (int c = 0; c < 8; ++c) {
                int m = mg + 16 * c;
                float s2 = acc[qq][c] * INV_SQRT_EMB;
                float e  = __builtin_amdgcn_exp2f(s2 * (2.0f * LOG2E));   // saturates fine
                float rc = __builtin_amdgcn_rcpf(e + 1.0f);
                float mv = mrow[m];
                float pv = __builtin_amdgcn_exp2f((mv - 20.0f * rc) * LOG2E); // -inf -> 0
                pr[qq][t * 8 + c] = pv;
                psum[qq] += pv;
            }
        }
    }

    #pragma unroll
    for (int qq = 0; qq < 2; ++qq) {
        float s = psum[qq];
        s += __shfl_xor(s, 1);
        s += __shfl_xor(s, 2);
        s += __shfl_xor(s, 4);
        s += __shfl_xor(s, 8);
        psum[qq] = s;
    }

    #pragma unroll
    for (int qq = 0; qq < 2; ++qq) {
        const int q = q0 + qg * 2 + qq;
        float* orow = OUT + (b * NQn + q) * NNn;
        if (psum[qq] == 0.0f) {
            #pragma unroll
            for (int t = 0; t < 4; ++t)
                #pragma unroll
                for (int c = 0; c < 8; ++c) {
                    int m = t * 128 + mg + 16 * c;
                    orow[m] = (m == 0) ? 1.0f : 0.0f;
                }
        } else {
            float inv = __builtin_amdgcn_rcpf(psum[qq]);
            #pragma unroll
            for (int t = 0; t < 4; ++t)
                #pragma unroll
                for (int c = 0; c < 8; ++c)
                    orow[t * 128 + mg + 16 * c] = pr[qq][t * 8 + c] * inv;
        }
    }
}

// ---------------------------------------------------------------------------
extern "C" void kernel_launch(void* const* d_in, const int* in_sizes, int n_in,
                              void* d_out, int out_size, void* d_ws, size_t ws_size,
                              hipStream_t stream) {
    const float* enc_last  = (const float*)d_in[0];   // [B,NQ,128]
    const float* attr      = (const float*)d_in[1];   // [B,NQ,1]
    const float* enc_nodes = (const float*)d_in[2];   // [B,NN,128]
    const float* mask      = (const float*)d_in[3];   // [B,NQ,NN]
    const float* Wq        = (const float*)d_in[4];   // [129,128]
    const float* Wk        = (const float*)d_in[5];   // [128,128]
    const float* Wv        = (const float*)d_in[6];   // [128,128]
    const float* Wcomb     = (const float*)d_in[7];   // [128,128]
    const float* bcomb     = (const float*)d_in[8];   // [128]
    float* out = (float*)d_out;

    float* Kbuf = (float*)d_ws;                         // [B*NN,128] 16.8MB
    float* Vbuf = Kbuf + (size_t)NB * NNn * 128;        // [B*NN,128] 16.8MB
    float* Qbuf = Vbuf + (size_t)NB * NNn * 128;        // [B*NQ,128]  8.4MB
    float* P0   = Qbuf + (size_t)NB * NQn * 128;        // 8.4MB
    float* P1   = P0   + (size_t)NB * NQn * 128;        // 8.4MB
    float* P2   = P1   + (size_t)NB * NQn * 128;        // 8.4MB
    float* P3   = P2   + (size_t)NB * NQn * 128;        // 8.4MB
    float* L0   = P3   + (size_t)NB * NQn * 128;        // 0.5MB
    float* L1   = L0   + (size_t)NB * NQn * 8;
    float* L2   = L1   + (size_t)NB * NQn * 8;
    float* L3   = L2   + (size_t)NB * NQn * 8;
    unsigned char* maskT8 = (unsigned char*)(L3 + (size_t)NB * NQn * 8);  // 8.4MB
    float* MH   = Qbuf;   // alias: Qbuf dead after attn; proj_comb writes, final reads

    // mask -> transposed u8 [b][n][q]
    mask_transpose<<<dim3(NB, NQn / 64, NNn / 64), 256, 0, stream>>>(mask, maskT8);
    // K,V projections (dual-pass over shared X tile)
    proj_kernel<<<dim3(NB * NNn / 64, 2), 256, 0, stream>>>(
        enc_nodes, Wk, Wv, nullptr, nullptr, nullptr, Kbuf, Vbuf);
    // Q projection (concat attr handled as rank-1 term with Wq row 128)
    proj_kernel<<<dim3(NB * NQn / 64, 2), 256, 0, stream>>>(
        enc_last, Wq, nullptr, Wq + 128 * 128, attr, nullptr, Qbuf, nullptr);
    // masked multi-head attention: 4q/lane, 4 node-splits (champion)
    attn_kernel<<<dim3(NB, 4), 512, 0, stream>>>(
        Qbuf, Kbuf, Vbuf, (const unsigned int*)maskT8,
        P0, P1, P2, P3, L0, L1, L2, L3);
    // combine projection + bias, 4-way merge fused into staging
    proj_comb_kernel<<<dim3(NB * NQn / 64, 2), 256, 0, stream>>>(
        P0, P1, P2, P3, L0, L1, L2, L3, Vbuf, Wcomb, bcomb, MH);
    // compatibility score + tanh clip + masked softmax
    final_kernel<<<dim3(NB * NQn / 64), 512, 0, stream>>>(
        MH, enc_nodes, mask, out);
}